// Round 1
// baseline (576.897 us; speedup 1.0000x reference)
//
#include <hip/hip_runtime.h>
#include <math.h>

// Problem constants
#define NCLS   19
#define KPC    100
#define NA     1900       // anchors
#define NAP    1920       // padded anchor cols (multiple of 64)
#define NM     20000      // memory rows
#define NMP    20096      // padded memory cols (multiple of 64)
#define NC     21900      // contrast rows = NA + NM
#define NCP    21952      // padded contrast (multiple of 64)
#define D      256        // feature dim
#define HW     16384      // 128*128
#define NPIX   131072     // 8*128*128
#define INV_T  10.0f      // 1/TEMP

// workspace byte offsets
#define WS_IDX   0
#define WS_ROWS  7680
#define WS_ROWP  15360
#define WS_ROWC  23040
#define WS_CLAB  30720
#define WS_AT    118784
#define WS_MT    2084864
// total ~22.7 MB

// ---------------- K0: zero accumulators + build contrast labels ----------------
__global__ void init_kernel(float* rowS, float* rowP, float* rowC, int* clab,
                            const int* __restrict__ memlab) {
    int i = blockIdx.x * 256 + threadIdx.x;
    if (i < NAP) { rowS[i] = 0.f; rowP[i] = 0.f; rowC[i] = 0.f; }
    if (i < NCP) {
        clab[i] = (i < NA) ? (i / KPC) : ((i < NC) ? memlab[i - NA] : -1);
    }
}

// ---------------- K1: first-K-per-class sampler (ascending order) ----------------
__global__ void sample_kernel(const int* __restrict__ labels, int* __restrict__ idx) {
    const int c = blockIdx.x;          // class
    const int t = threadIdx.x;         // 256 threads
    const int wave = t >> 6, lane = t & 63;
    __shared__ int s_base;
    __shared__ int s_wavecnt[4];
    if (t == 0) s_base = 0;
    __syncthreads();
    for (int start = 0; start < NPIX; start += 256) {
        const int i = start + t;
        const bool pred = (labels[i] == c);
        const unsigned long long b = __ballot(pred);
        if (lane == 0) s_wavecnt[wave] = __popcll(b);
        __syncthreads();                       // publish wavecnt (and prev s_base update)
        const int base = s_base;
        int wbase = 0;
        for (int w = 0; w < wave; ++w) wbase += s_wavecnt[w];
        const int chunk_total = s_wavecnt[0] + s_wavecnt[1] + s_wavecnt[2] + s_wavecnt[3];
        if (pred) {
            const int rank = base + wbase + __popcll(b & ((1ULL << lane) - 1ULL));
            if (rank < KPC) idx[c * KPC + rank] = i;
        }
        __syncthreads();                       // everyone read s_base
        if (t == 0) s_base = base + chunk_total;
        if (base + chunk_total >= KPC) break;  // uniform condition
    }
}

// ---------------- K2: gather + normalize anchors -> At[k][NAP] (K-major) ----------------
__global__ void anchor_norm_kernel(const float* __restrict__ pixel,
                                   const int* __restrict__ idx,
                                   float* __restrict__ At) {
    const int n = blockIdx.x;          // 0..NAP-1
    const int d = threadIdx.x;         // 0..255
    if (n >= NA) { At[(size_t)d * NAP + n] = 0.f; return; }
    const int p = idx[n];
    const int b = p >> 14;
    const int hw = p & (HW - 1);
    const float v = pixel[((size_t)(b * D + d)) * HW + hw];
    float ssq = v * v;
    for (int o = 32; o; o >>= 1) ssq += __shfl_xor(ssq, o, 64);
    __shared__ float red[4];
    if ((d & 63) == 0) red[d >> 6] = ssq;
    __syncthreads();
    const float tot = red[0] + red[1] + red[2] + red[3];
    const float inv = 1.0f / fmaxf(sqrtf(tot), 1e-12f);
    At[(size_t)d * NAP + n] = v * inv;
}

// ---------------- K3: normalize memory feats -> Mt[k][NMP] (K-major) ----------------
__global__ void memory_norm_kernel(const float* __restrict__ mem, float* __restrict__ Mt) {
    const int r = blockIdx.x;          // 0..NMP-1
    const int d = threadIdx.x;
    if (r >= NM) { Mt[(size_t)d * NMP + r] = 0.f; return; }
    const float v = mem[(size_t)r * D + d];
    float ssq = v * v;
    for (int o = 32; o; o >>= 1) ssq += __shfl_xor(ssq, o, 64);
    __shared__ float red[4];
    if ((d & 63) == 0) red[d >> 6] = ssq;
    __syncthreads();
    const float tot = red[0] + red[1] + red[2] + red[3];
    const float inv = 1.0f / fmaxf(sqrtf(tot), 1e-12f);
    Mt[(size_t)d * NMP + r] = v * inv;
}

// ---------------- K4: fused GEMM + contrastive epilogue ----------------
// Block: 64 anchor rows x (strided set of 64-col contrast tiles), 256 threads,
// 4x4 micro-tile per thread. LDS: As full-K (64KB) + Cs one k-chunk (16KB) = 80KB
// -> 2 blocks/CU.
__global__ __launch_bounds__(256, 2)
void gemm_epilogue_kernel(const float* __restrict__ At, const float* __restrict__ Mt,
                          const int* __restrict__ clab,
                          float* __restrict__ rowS, float* __restrict__ rowP,
                          float* __restrict__ rowC) {
    __shared__ __align__(16) float As[256 * 64];   // [k][anchor col]
    __shared__ __align__(16) float Cs[64 * 64];    // [k within chunk][contrast col]
    const int tid = threadIdx.x;
    const int tx = tid & 15, ty = tid >> 4;
    const int n0 = blockIdx.y * 64;

    // stage As: coalesced from K-major At, transposed-to-tile layout
    {
        const int col4 = (tid & 15) * 4;
        const int kr = tid >> 4;
        for (int i = 0; i < 16; ++i) {
            const int k = kr + i * 16;
            const float4 v = *reinterpret_cast<const float4*>(At + (size_t)k * NAP + n0 + col4);
            *reinterpret_cast<float4*>(As + k * 64 + col4) = v;
        }
    }

    float regS[4] = {0.f, 0.f, 0.f, 0.f};
    float regP[4] = {0.f, 0.f, 0.f, 0.f};
    float regC[4] = {0.f, 0.f, 0.f, 0.f};
    int nlab[4];
    for (int i = 0; i < 4; ++i) {
        const int n = n0 + ty * 4 + i;
        nlab[i] = (n < NA) ? (n / KPC) : -9;
    }

    for (int mt = blockIdx.x; mt < NCP / 64; mt += gridDim.x) {
        const int m0 = mt * 64;
        float acc[4][4] = {{0.f}};
        for (int kc = 0; kc < 4; ++kc) {
            __syncthreads();
            {   // stage Cs chunk: source is At for m<NA else Mt (split is float4-aligned)
                const int col4 = (tid & 15) * 4;
                const int kr = tid >> 4;
                const int m = m0 + col4;
                const float* src = (m < NA) ? (At + m) : (Mt + (m - NA));
                const size_t stride = (m < NA) ? (size_t)NAP : (size_t)NMP;
                for (int i = 0; i < 4; ++i) {
                    const int kk = kr + i * 16;
                    const float4 v = *reinterpret_cast<const float4*>(src + (size_t)(kc * 64 + kk) * stride);
                    *reinterpret_cast<float4*>(Cs + kk * 64 + col4) = v;
                }
            }
            __syncthreads();
            #pragma unroll 4
            for (int kk = 0; kk < 64; ++kk) {
                const float4 a = *reinterpret_cast<const float4*>(As + (kc * 64 + kk) * 64 + ty * 4);
                const float4 c = *reinterpret_cast<const float4*>(Cs + kk * 64 + tx * 4);
                acc[0][0] += a.x * c.x; acc[0][1] += a.x * c.y; acc[0][2] += a.x * c.z; acc[0][3] += a.x * c.w;
                acc[1][0] += a.y * c.x; acc[1][1] += a.y * c.y; acc[1][2] += a.y * c.z; acc[1][3] += a.y * c.w;
                acc[2][0] += a.z * c.x; acc[2][1] += a.z * c.y; acc[2][2] += a.z * c.z; acc[2][3] += a.z * c.w;
                acc[3][0] += a.w * c.x; acc[3][1] += a.w * c.y; acc[3][2] += a.w * c.z; acc[3][3] += a.w * c.w;
            }
        }
        // fused contrastive epilogue for this 64x64 tile
        #pragma unroll
        for (int j = 0; j < 4; ++j) {
            const int m = m0 + tx * 4 + j;
            if (m >= NC) continue;
            const int cl = clab[m];
            #pragma unroll
            for (int i = 0; i < 4; ++i) {
                const int n = n0 + ty * 4 + i;
                if (n >= NA || m == n) continue;   // row pad / self-contrast mask
                const float l = acc[i][j] * INV_T;
                regS[i] += __expf(l);
                if (cl == nlab[i]) { regP[i] += l; regC[i] += 1.f; }
            }
        }
    }

    // reduce across the 16 tx lanes sharing each row, then one atomic per row
    for (int i = 0; i < 4; ++i) {
        float s = regS[i], p = regP[i], c = regC[i];
        for (int o = 1; o < 16; o <<= 1) {
            s += __shfl_xor(s, o, 64);
            p += __shfl_xor(p, o, 64);
            c += __shfl_xor(c, o, 64);
        }
        if (tx == 0) {
            const int n = n0 + ty * 4 + i;
            if (n < NA) {
                atomicAdd(&rowS[n], s);
                atomicAdd(&rowP[n], p);
                atomicAdd(&rowC[n], c);
            }
        }
    }
}

// ---------------- K5: final loss ----------------
__global__ void finalize_kernel(const float* __restrict__ rowS, const float* __restrict__ rowP,
                                const float* __restrict__ rowC, float* __restrict__ out) {
    const int t = threadIdx.x;
    float sum = 0.f, nval = 0.f;
    for (int n = t; n < NA; n += 256) {
        const float cnt = rowC[n];
        const float logS = logf(rowS[n] + 1e-12f);
        const float mean = (rowP[n] - cnt * logS) / fmaxf(cnt, 1.0f);
        if (cnt > 0.f) { sum += mean; nval += 1.f; }
    }
    for (int o = 32; o; o >>= 1) {
        sum += __shfl_xor(sum, o, 64);
        nval += __shfl_xor(nval, o, 64);
    }
    __shared__ float rs[4], rn[4];
    if ((t & 63) == 0) { rs[t >> 6] = sum; rn[t >> 6] = nval; }
    __syncthreads();
    if (t == 0) {
        const float s = rs[0] + rs[1] + rs[2] + rs[3];
        const float nv = rn[0] + rn[1] + rn[2] + rn[3];
        out[0] = -(0.1f / 0.07f) * (s / fmaxf(nv, 1.f));
    }
}

extern "C" void kernel_launch(void* const* d_in, const int* in_sizes, int n_in,
                              void* d_out, int out_size, void* d_ws, size_t ws_size,
                              hipStream_t stream) {
    const float* pixel  = (const float*)d_in[0];   // [8,256,128,128]
    const int*   labels = (const int*)d_in[1];     // [8,128,128]
    const float* mem    = (const float*)d_in[2];   // [20000,256]
    const int*   memlab = (const int*)d_in[3];     // [20000]
    char* ws = (char*)d_ws;
    int*   idx  = (int*)(ws + WS_IDX);
    float* rowS = (float*)(ws + WS_ROWS);
    float* rowP = (float*)(ws + WS_ROWP);
    float* rowC = (float*)(ws + WS_ROWC);
    int*   clab = (int*)(ws + WS_CLAB);
    float* At   = (float*)(ws + WS_AT);
    float* Mt   = (float*)(ws + WS_MT);
    float* out  = (float*)d_out;

    init_kernel<<<dim3(86), dim3(256), 0, stream>>>(rowS, rowP, rowC, clab, memlab);
    sample_kernel<<<dim3(NCLS), dim3(256), 0, stream>>>(labels, idx);
    anchor_norm_kernel<<<dim3(NAP), dim3(256), 0, stream>>>(pixel, idx, At);
    memory_norm_kernel<<<dim3(NMP), dim3(256), 0, stream>>>(mem, Mt);
    gemm_epilogue_kernel<<<dim3(17, 30), dim3(256), 0, stream>>>(At, Mt, clab, rowS, rowP, rowC);
    finalize_kernel<<<dim3(1), dim3(256), 0, stream>>>(rowS, rowP, rowC, out);
}

// Round 2
// 263.341 us; speedup vs baseline: 2.1907x; 2.1907x over previous
//
#include <hip/hip_runtime.h>
#include <hip/hip_bf16.h>
#include <math.h>

// Problem constants
#define NCLS   19
#define KPC    100
#define NA     1900       // anchors (also first NA contrast cols)
#define NM     20000      // memory rows
#define NC     21900      // contrast rows = NA + NM
#define NCP2   22016      // contrast cols padded to multiple of 128
#define D      256        // feature dim
#define HW     16384      // 128*128
#define NPIX   131072     // 8*128*128
#define NT_M   15         // 1920/128 m-tiles
#define NT_N   172        // 22016/128 n-tiles

typedef __attribute__((ext_vector_type(8))) short bf16x8;
typedef __attribute__((ext_vector_type(4))) float f32x4;

// workspace byte offsets
#define WS_IDX   0         // 1900 ints
#define WS_ROWS  7680      // 1920 f
#define WS_ROWP  15360
#define WS_ROWC  23040
#define WS_CLAB  30720     // 22016 ints
#define WS_CT2   118784    // bf16 [32 kq][22016 n][8] = 11,272,192 B
// total ~11.4 MB

__device__ __forceinline__ short f2bf(float x) {
    __hip_bfloat16 h = __float2bfloat16(x);
    return *(short*)&h;
}

// ---------------- K0: zero accumulators/pads + build contrast labels ----------------
__global__ void init_kernel(float* rowS, float* rowP, float* rowC, int* clab,
                            const int* __restrict__ memlab, short* __restrict__ Ct2) {
    const int i = blockIdx.x * 256 + threadIdx.x;
    if (i < NCP2) clab[i] = (i < NA) ? ((i * 5243) >> 19)
                                     : ((i < NC) ? memlab[i - NA] : -1);
    if (i < 1920) { rowS[i] = 0.f; rowP[i] = 0.f; rowC[i] = 0.f; }
    if (i < 32 * (NCP2 - NC)) {            // zero bf16 pad cols (n = 21900..22015)
        const int kq = i / (NCP2 - NC);
        const int n  = NC + i % (NCP2 - NC);
        bf16x8 z = {};
        *(bf16x8*)(Ct2 + ((size_t)kq * NCP2 + n) * 8) = z;
    }
}

// ---------------- K1: first-K-per-class sampler (ascending order) ----------------
__global__ void sample_kernel(const int* __restrict__ labels, int* __restrict__ idx) {
    const int c = blockIdx.x;
    const int t = threadIdx.x;
    const int wave = t >> 6, lane = t & 63;
    __shared__ int s_base;
    __shared__ int s_wavecnt[4];
    if (t == 0) s_base = 0;
    __syncthreads();
    for (int start = 0; start < NPIX; start += 256) {
        const int i = start + t;
        const bool pred = (labels[i] == c);
        const unsigned long long b = __ballot(pred);
        if (lane == 0) s_wavecnt[wave] = __popcll(b);
        __syncthreads();
        const int base = s_base;
        int wbase = 0;
        for (int w = 0; w < wave; ++w) wbase += s_wavecnt[w];
        const int chunk_total = s_wavecnt[0] + s_wavecnt[1] + s_wavecnt[2] + s_wavecnt[3];
        if (pred) {
            const int rank = base + wbase + __popcll(b & ((1ULL << lane) - 1ULL));
            if (rank < KPC) idx[c * KPC + rank] = i;
        }
        __syncthreads();
        if (t == 0) s_base = base + chunk_total;
        if (base + chunk_total >= KPC) break;
    }
}

// ---------------- K2: gather + normalize anchors -> Ct2 cols 0..1899 ----------------
// 8 anchors per block, 32 threads per anchor (one kq=8-d chunk each)
__global__ void anchor_kernel(const float* __restrict__ pixel, const int* __restrict__ idx,
                              short* __restrict__ Ct2) {
    const int t = threadIdx.x;
    const int a = blockIdx.x * 8 + (t >> 5);
    const int kq = t & 31;
    if (a >= NA) return;
    const int p = idx[a];
    const int b = p >> 14;
    const int hw = p & (HW - 1);
    const float* base = pixel + ((size_t)(b * D + kq * 8)) * HW + hw;
    float v[8];
    float ssq = 0.f;
    #pragma unroll
    for (int j = 0; j < 8; ++j) { v[j] = base[(size_t)j * HW]; ssq += v[j] * v[j]; }
    #pragma unroll
    for (int o = 16; o; o >>= 1) ssq += __shfl_xor(ssq, o, 32);
    const float inv = 1.0f / fmaxf(sqrtf(ssq), 1e-12f);
    bf16x8 out;
    #pragma unroll
    for (int j = 0; j < 8; ++j) out[j] = f2bf(v[j] * inv);
    *(bf16x8*)(Ct2 + ((size_t)kq * NCP2 + a) * 8) = out;
}

// ---------------- K3: normalize memory feats -> Ct2 cols 1900..21899 ----------------
__global__ void memory_kernel(const float* __restrict__ mem, short* __restrict__ Ct2) {
    const int t = threadIdx.x;
    const int r = blockIdx.x * 8 + (t >> 5);
    const int kq = t & 31;
    const float4 v0 = *(const float4*)(mem + (size_t)r * D + kq * 8);
    const float4 v1 = *(const float4*)(mem + (size_t)r * D + kq * 8 + 4);
    float ssq = v0.x*v0.x + v0.y*v0.y + v0.z*v0.z + v0.w*v0.w
              + v1.x*v1.x + v1.y*v1.y + v1.z*v1.z + v1.w*v1.w;
    #pragma unroll
    for (int o = 16; o; o >>= 1) ssq += __shfl_xor(ssq, o, 32);
    const float inv = 1.0f / fmaxf(sqrtf(ssq), 1e-12f);
    bf16x8 out;
    out[0] = f2bf(v0.x * inv); out[1] = f2bf(v0.y * inv);
    out[2] = f2bf(v0.z * inv); out[3] = f2bf(v0.w * inv);
    out[4] = f2bf(v1.x * inv); out[5] = f2bf(v1.y * inv);
    out[6] = f2bf(v1.z * inv); out[7] = f2bf(v1.w * inv);
    *(bf16x8*)(Ct2 + ((size_t)kq * NCP2 + NA + r) * 8) = out;
}

// ---------------- K4: MFMA GEMM + fused contrastive epilogue ----------------
// 128x128 tile, 4 waves in 2x2, each wave 64x64 via 4x4 grid of 16x16x32 bf16 MFMA.
// LDS [kq][row][8] layout: conflict-balanced for ds_read_b128 frags AND matches
// global_load_lds lane-contiguous placement from the [kq][n][8] global layout.
__global__ __launch_bounds__(256, 3)
void mfma_gemm_kernel(const short* __restrict__ Ct2, const int* __restrict__ clab,
                      float* __restrict__ rowS, float* __restrict__ rowP,
                      float* __restrict__ rowC) {
    __shared__ __align__(16) short As[8 * 128 * 8];   // 16 KB
    __shared__ __align__(16) short Bs[8 * 128 * 8];   // 16 KB
    const int tid  = threadIdx.x;
    const int lane = tid & 63;
    const int w    = tid >> 6;           // wave 0..3
    const int wm   = w >> 1, wn = w & 1;
    const int m0   = blockIdx.x * 128;
    const int n0   = blockIdx.y * 128;
    const int quad = lane >> 4;
    const int l16  = lane & 15;

    f32x4 acc[4][4] = {};                // [mi][ni]

    for (int kc = 0; kc < 4; ++kc) {
        #pragma unroll
        for (int i = 0; i < 4; ++i) {
            const int bl = (w * 4 + i) * 64;   // 0..960 step 64, wave-uniform
            const int kq = bl >> 7;            // 0..7
            const int ml = bl & 127;           // 0 or 64
            const size_t gA = ((size_t)(kc * 8 + kq) * NCP2 + m0 + ml + lane) * 8;
            __builtin_amdgcn_global_load_lds(
                (const __attribute__((address_space(1))) void*)(Ct2 + gA),
                (__attribute__((address_space(3))) void*)(As + (size_t)bl * 8 + lane * 8),
                16, 0, 0);
            const size_t gB = ((size_t)(kc * 8 + kq) * NCP2 + n0 + ml + lane) * 8;
            __builtin_amdgcn_global_load_lds(
                (const __attribute__((address_space(1))) void*)(Ct2 + gB),
                (__attribute__((address_space(3))) void*)(Bs + (size_t)bl * 8 + lane * 8),
                16, 0, 0);
        }
        __syncthreads();
        #pragma unroll
        for (int ks = 0; ks < 2; ++ks) {
            const int kqb = ks * 4 + quad;
            bf16x8 af[4], bfr[4];
            #pragma unroll
            for (int mi = 0; mi < 4; ++mi)
                af[mi] = *(const bf16x8*)(As + ((kqb * 128) + wm * 64 + mi * 16 + l16) * 8);
            #pragma unroll
            for (int ni = 0; ni < 4; ++ni)
                bfr[ni] = *(const bf16x8*)(Bs + ((kqb * 128) + wn * 64 + ni * 16 + l16) * 8);
            #pragma unroll
            for (int mi = 0; mi < 4; ++mi)
                #pragma unroll
                for (int ni = 0; ni < 4; ++ni)
                    acc[mi][ni] = __builtin_amdgcn_mfma_f32_16x16x32_bf16(
                        af[mi], bfr[ni], acc[mi][ni], 0, 0, 0);
        }
        __syncthreads();
    }

    // fused epilogue: logits -> exp / same-class sums, one atomic triple per m-row
    int nIdx[4], nLab[4];
    #pragma unroll
    for (int ni = 0; ni < 4; ++ni) {
        const int n = n0 + wn * 64 + ni * 16 + l16;
        nIdx[ni] = n;
        nLab[ni] = (n < NC) ? clab[n] : -1;
    }
    #pragma unroll
    for (int mi = 0; mi < 4; ++mi) {
        #pragma unroll
        for (int r = 0; r < 4; ++r) {
            const int m = m0 + wm * 64 + mi * 16 + quad * 4 + r;   // C/D: row=(lane>>4)*4+reg
            const int mlab = (m * 5243) >> 19;                     // m/100
            float s = 0.f, p = 0.f, cnt = 0.f;
            #pragma unroll
            for (int ni = 0; ni < 4; ++ni) {
                const int n = nIdx[ni];
                if (n < NC && n != m) {
                    const float l = acc[mi][ni][r] * 10.0f;
                    s += __expf(l);
                    if (nLab[ni] == mlab) { p += l; cnt += 1.f; }
                }
            }
            for (int o = 1; o < 16; o <<= 1) {
                s   += __shfl_xor(s, o, 64);
                p   += __shfl_xor(p, o, 64);
                cnt += __shfl_xor(cnt, o, 64);
            }
            if (l16 == 0 && m < NA) {
                atomicAdd(&rowS[m], s);
                atomicAdd(&rowP[m], p);
                atomicAdd(&rowC[m], cnt);
            }
        }
    }
}

// ---------------- K5: final loss ----------------
__global__ void finalize_kernel(const float* __restrict__ rowS, const float* __restrict__ rowP,
                                const float* __restrict__ rowC, float* __restrict__ out) {
    const int t = threadIdx.x;
    float sum = 0.f, nval = 0.f;
    for (int n = t; n < NA; n += 256) {
        const float cnt = rowC[n];
        const float logS = logf(rowS[n] + 1e-12f);
        const float mean = (rowP[n] - cnt * logS) / fmaxf(cnt, 1.0f);
        if (cnt > 0.f) { sum += mean; nval += 1.f; }
    }
    for (int o = 32; o; o >>= 1) {
        sum += __shfl_xor(sum, o, 64);
        nval += __shfl_xor(nval, o, 64);
    }
    __shared__ float rs[4], rn[4];
    if ((t & 63) == 0) { rs[t >> 6] = sum; rn[t >> 6] = nval; }
    __syncthreads();
    if (t == 0) {
        const float s = rs[0] + rs[1] + rs[2] + rs[3];
        const float nv = rn[0] + rn[1] + rn[2] + rn[3];
        out[0] = -(0.1f / 0.07f) * (s / fmaxf(nv, 1.f));
    }
}

extern "C" void kernel_launch(void* const* d_in, const int* in_sizes, int n_in,
                              void* d_out, int out_size, void* d_ws, size_t ws_size,
                              hipStream_t stream) {
    const float* pixel  = (const float*)d_in[0];   // [8,256,128,128]
    const int*   labels = (const int*)d_in[1];     // [8,128,128]
    const float* mem    = (const float*)d_in[2];   // [20000,256]
    const int*   memlab = (const int*)d_in[3];     // [20000]
    char* ws = (char*)d_ws;
    int*   idx  = (int*)(ws + WS_IDX);
    float* rowS = (float*)(ws + WS_ROWS);
    float* rowP = (float*)(ws + WS_ROWP);
    float* rowC = (float*)(ws + WS_ROWC);
    int*   clab = (int*)(ws + WS_CLAB);
    short* Ct2  = (short*)(ws + WS_CT2);
    float* out  = (float*)d_out;

    init_kernel<<<dim3(86), dim3(256), 0, stream>>>(rowS, rowP, rowC, clab, memlab, Ct2);
    sample_kernel<<<dim3(NCLS), dim3(256), 0, stream>>>(labels, idx);
    anchor_kernel<<<dim3(238), dim3(256), 0, stream>>>(pixel, idx, Ct2);
    memory_kernel<<<dim3(2500), dim3(256), 0, stream>>>(mem, Ct2);
    mfma_gemm_kernel<<<dim3(NT_M, NT_N), dim3(256), 0, stream>>>(Ct2, clab, rowS, rowP, rowC);
    finalize_kernel<<<dim3(1), dim3(256), 0, stream>>>(rowS, rowP, rowC, out);
}